// Round 1
// baseline (101.704 us; speedup 1.0000x reference)
//
#include <hip/hip_runtime.h>

// Output: (1, 9, 16, 9, 256, 256) f32 — out[d][c][a][y][x]
// Input:  (1, 16, 9, 256, 256)  f32 — in[c][a][y][x]
// t = (d-4)*(a-4); out = in[c][a][y-t][x-t] if in-bounds else 0.

__global__ __launch_bounds__(256) void cost_volume_kernel(
    const float* __restrict__ in, float* __restrict__ out)
{
    // blockIdx.y = d*144 + c*9 + a  (1296 values)
    // blockIdx.x = y/4 (64 values); threadIdx.y = y%4 row-in-block
    // threadIdx.x = x/4 (64 lanes, each does a float4)
    int dca = blockIdx.y;
    int d = dca / 144;
    int rem = dca - d * 144;
    int c = rem / 9;
    int a = rem - c * 9;

    int y = blockIdx.x * 4 + threadIdx.y;
    int x = threadIdx.x * 4;

    int t  = (d - 4) * (a - 4);
    int yy = y - t;

    long out_off = ((((long)d * 16 + c) * 9 + a) * 256L + y) * 256L + x;

    float4 v = make_float4(0.f, 0.f, 0.f, 0.f);
    if (yy >= 0 && yy < 256) {
        const float* __restrict__ row = in + (((long)c * 9 + a) * 256L + yy) * 256L;
        int xx = x - t;
        float vals[4];
        #pragma unroll
        for (int e = 0; e < 4; ++e) {
            int xe = xx + e;
            vals[e] = (xe >= 0 && xe < 256) ? row[xe] : 0.f;
        }
        v = make_float4(vals[0], vals[1], vals[2], vals[3]);
    }
    *reinterpret_cast<float4*>(out + out_off) = v;
}

extern "C" void kernel_launch(void* const* d_in, const int* in_sizes, int n_in,
                              void* d_out, int out_size, void* d_ws, size_t ws_size,
                              hipStream_t stream)
{
    const float* in = (const float*)d_in[0];
    float* out = (float*)d_out;

    dim3 block(64, 4, 1);   // 256 threads = 4 waves
    dim3 grid(64, 1296, 1); // 64 y-groups x (9*16*9) d,c,a
    cost_volume_kernel<<<grid, block, 0, stream>>>(in, out);
}

// Round 2
// 71.944 us; speedup vs baseline: 1.4137x; 1.4137x over previous
//
#include <hip/hip_runtime.h>

// Output: (1, 9, 16, 9, 256, 256) f32 — out[d][c][a][y][x]
// Input:  (1, 16, 9, 256, 256)  f32 — in[c][a][y][x]
// t = (d-4)*(a-4); out[d][c][a][y][x] = in[c][a][y-t][x-t] if in-bounds else 0.
//
// One block = one (c,a) slice x one 16-row y-tile, ALL 9 d values.
// Input rows staged once into LDS (16 + 2*4|a-4| <= 48 rows = 48 KB),
// then 9 shifted copies are written out. Cuts input HBM/L3 re-reads 9x.

#define RTILE 16          // output rows per block
#define MAXROWS 48        // RTILE + 2*16 worst-case halo (a=0 or a=8)

__global__ __launch_bounds__(256) void cost_volume_kernel(
    const float* __restrict__ in, float* __restrict__ out)
{
    __shared__ float lds[MAXROWS * 256];   // 48 KB

    // blockIdx.y = c*9 + a (144); blockIdx.x = y-tile (16)
    int ca = blockIdx.y;
    int c = ca / 9;
    int a = ca - c * 9;
    int y0 = blockIdx.x * RTILE;

    int tx = threadIdx.x;   // 0..63
    int ty = threadIdx.y;   // 0..3

    int a4 = a - 4;
    int H = 4 * (a4 < 0 ? -a4 : a4);   // max |t|
    int nrows = RTILE + 2 * H;         // rows to stage
    int base = y0 - H;                 // first (possibly OOB) input row

    // ---- stage input rows [base, base+nrows) into LDS, zero-padding OOB ----
    const float* __restrict__ slice = in + ((long)ca * 256) * 256;
    for (int r0 = 0; r0 < nrows; r0 += 4) {
        int r = r0 + ty;
        if (r < nrows) {
            int g = base + r;
            float4 v = make_float4(0.f, 0.f, 0.f, 0.f);
            if (g >= 0 && g < 256)
                v = *reinterpret_cast<const float4*>(slice + g * 256 + tx * 4);
            *reinterpret_cast<float4*>(&lds[r * 256 + tx * 4]) = v;
        }
    }
    __syncthreads();

    // ---- emit all 9 d-shifted copies from LDS ----
    #pragma unroll
    for (int d = 0; d < 9; ++d) {
        int t = (d - 4) * a4;
        long obase = (((long)(d * 16 + c) * 9 + a) * 256L);
        for (int yb = ty; yb < RTILE; yb += 4) {
            int y = y0 + yb;
            int lr = y - t - base;                 // always in [0, nrows)
            const float* __restrict__ lrow = &lds[lr * 256];
            float* __restrict__ orow = out + (obase + y) * 256L;
            #pragma unroll
            for (int e = 0; e < 4; ++e) {
                int x = tx + 64 * e;               // lane-stride-1 -> no LDS bank conflicts
                int xx = x - t;
                float v = (xx >= 0 && xx < 256) ? lrow[xx] : 0.f;
                __builtin_nontemporal_store(v, orow + x);
            }
        }
    }
}

extern "C" void kernel_launch(void* const* d_in, const int* in_sizes, int n_in,
                              void* d_out, int out_size, void* d_ws, size_t ws_size,
                              hipStream_t stream)
{
    const float* in = (const float*)d_in[0];
    float* out = (float*)d_out;

    dim3 block(64, 4, 1);    // 256 threads = 4 waves
    dim3 grid(16, 144, 1);   // 16 y-tiles x (16 c * 9 a)
    cost_volume_kernel<<<grid, block, 0, stream>>>(in, out);
}

// Round 3
// 70.572 us; speedup vs baseline: 1.4411x; 1.0194x over previous
//
#include <hip/hip_runtime.h>

// Output: (1, 9, 16, 9, 256, 256) f32 — out[d][c][a][y][x]
// Input:  (1, 16, 9, 256, 256)  f32 — in[c][a][y][x]
// t = (d-4)*(a-4); out[d][c][a][y][x] = in[c][a][y-t][x-t] if in-bounds else 0.
//
// SCATTER decomposition: one block = one (c,a) slice x one 16-row INPUT tile
// (no halo — input read exactly once). For each d, the tile's rows g land at
// output rows y = g + t (clipped). Output rows with y-t out of [0,256) are
// all-zero and are zero-filled by the first (t>0) / last (t<0) tile block,
// so every output row is written exactly once.

#define RTILE 16

__global__ __launch_bounds__(256) void cost_volume_kernel(
    const float* __restrict__ in, float* __restrict__ out)
{
    __shared__ float lds[RTILE * 256];   // 16 KB -> 8 blocks/CU

    int ca = blockIdx.y;                  // c*9 + a
    int c = ca / 9;
    int a = ca - c * 9;
    int a4 = a - 4;
    int g0 = blockIdx.x * RTILE;          // first input row of this tile

    int tx = threadIdx.x;                 // 0..63
    int ty = threadIdx.y;                 // 0..3 (== wave id)

    // ---- stage 16 input rows (all in-bounds, no halo) ----
    const float* __restrict__ slice = in + (long)ca * 256 * 256;
    #pragma unroll
    for (int r0 = 0; r0 < RTILE; r0 += 4) {
        int r = r0 + ty;
        *reinterpret_cast<float4*>(&lds[r * 256 + tx * 4]) =
            *reinterpret_cast<const float4*>(slice + (long)(g0 + r) * 256 + tx * 4);
    }
    __syncthreads();

    // ---- scatter to all 9 d-shifted output planes ----
    #pragma unroll
    for (int d = 0; d < 9; ++d) {
        int t = (d - 4) * a4;
        float* __restrict__ oplane = out + ((long)(d * 16 + c) * 9 + a) * 256L * 256L;

        // shifted-copy rows: y = g + t for g in tile, clipped to [0,256)
        for (int yb = ty; yb < RTILE; yb += 4) {       // wave-uniform y per iter
            int y = g0 + yb + t;
            if (y < 0 || y >= 256) continue;
            const float* __restrict__ lrow = &lds[yb * 256];
            float* __restrict__ orow = oplane + (long)y * 256;
            #pragma unroll
            for (int e = 0; e < 4; ++e) {
                int x = tx + 64 * e;                   // lane-stride-1: coalesced store,
                int xx = x - t;                        // conflict-free LDS read
                float v = (xx >= 0 && xx < 256) ? lrow[xx] : 0.f;
                __builtin_nontemporal_store(v, orow + x);
            }
        }

        // zero-fill the uncovered rows (only edge tiles have duty)
        int z0 = 0, zn = 0;
        if (t > 0 && g0 == 0)                { z0 = 0;       zn = t;  }
        else if (t < 0 && g0 == 256 - RTILE) { z0 = 256 + t; zn = -t; }
        for (int yb = ty; yb < zn; yb += 4) {
            float* __restrict__ orow = oplane + (long)(z0 + yb) * 256;
            #pragma unroll
            for (int e = 0; e < 4; ++e)
                __builtin_nontemporal_store(0.f, orow + tx + 64 * e);
        }
    }
}

extern "C" void kernel_launch(void* const* d_in, const int* in_sizes, int n_in,
                              void* d_out, int out_size, void* d_ws, size_t ws_size,
                              hipStream_t stream)
{
    const float* in = (const float*)d_in[0];
    float* out = (float*)d_out;

    dim3 block(64, 4, 1);    // 256 threads = 4 waves
    dim3 grid(16, 144, 1);   // 16 input y-tiles x (16 c * 9 a)
    cost_volume_kernel<<<grid, block, 0, stream>>>(in, out);
}

// Round 5
// 67.591 us; speedup vs baseline: 1.5047x; 1.0441x over previous
//
#include <hip/hip_runtime.h>

// Output: (1, 9, 16, 9, 256, 256) f32 — out[d][c][a][y][x]
// Input:  (1, 16, 9, 256, 256)  f32 — in[c][a][y][x]
// t = (d-4)*(a-4); out[d][c][a][y][x] = in[c][a][y-t][x-t] if in-bounds else 0.
//
// Scatter decomposition (round 3) + dwordx4 nt stores (round 4):
// each lane stores an aligned float4 of the output row, built by funnel-
// shifting two ALIGNED float4 LDS chunks by the uniform shift t&3
// (compile-time via template switch). LDS reads stay lane-contiguous
// ds_read_b128 -> conflict-free. Zero rows distributed across y-tile blocks.

#define RTILE 16

typedef float vf4 __attribute__((ext_vector_type(4)));   // native vec for nt-store

template<int TR>
__device__ __forceinline__ void emit_plane(const float* __restrict__ lds_t,
                                           float* __restrict__ oplane,
                                           int g0, int t, int tq,
                                           int tx, int ty)
{
    for (int yb = ty; yb < RTILE; yb += 4) {          // wave-uniform row
        int y = g0 + yb + t;
        if (y < 0 || y >= 256) continue;
        const float* __restrict__ lrow = lds_t + yb * 256;
        float* __restrict__ orow = oplane + (long)y * 256;

        int m2 = tx - tq;                 // aligned chunk indices
        int m2c = m2 < 0 ? 0 : (m2 > 63 ? 63 : m2);
        vf4 B = *reinterpret_cast<const vf4*>(lrow + 4 * m2c);
        float w0, w1, w2, w3;
        if (TR == 0) {
            w0 = B.x; w1 = B.y; w2 = B.z; w3 = B.w;
        } else {
            int m1 = m2 - 1;
            int m1c = m1 < 0 ? 0 : (m1 > 63 ? 63 : m1);
            vf4 A = *reinterpret_cast<const vf4*>(lrow + 4 * m1c);
            float cc[8] = {A.x, A.y, A.z, A.w, B.x, B.y, B.z, B.w};
            w0 = cc[4 - TR]; w1 = cc[5 - TR];         // compile-time indices
            w2 = cc[6 - TR]; w3 = cc[7 - TR];
        }
        int x0 = 4 * tx;
        int lo = t, hi = 256 + t;                     // valid x: [t, 256+t)
        vf4 v;
        v.x = (x0 + 0 >= lo && x0 + 0 < hi) ? w0 : 0.f;
        v.y = (x0 + 1 >= lo && x0 + 1 < hi) ? w1 : 0.f;
        v.z = (x0 + 2 >= lo && x0 + 2 < hi) ? w2 : 0.f;
        v.w = (x0 + 3 >= lo && x0 + 3 < hi) ? w3 : 0.f;
        __builtin_nontemporal_store(v, reinterpret_cast<vf4*>(orow + x0));
    }
}

__global__ __launch_bounds__(256) void cost_volume_kernel(
    const float* __restrict__ in, float* __restrict__ out)
{
    __shared__ float lds_t[RTILE * 256];   // 16 KB

    int ca = blockIdx.y;                    // c*9 + a
    int c = ca / 9;
    int a = ca - c * 9;
    int a4 = a - 4;
    int g0 = blockIdx.x * RTILE;            // first input row of tile

    int tx = threadIdx.x;                   // 0..63
    int ty = threadIdx.y;                   // 0..3

    // ---- stage 16 input rows, no halo ----
    const float* __restrict__ slice = in + (long)ca * 65536;
    #pragma unroll
    for (int r0 = 0; r0 < RTILE; r0 += 4) {
        int r = r0 + ty;
        *reinterpret_cast<vf4*>(&lds_t[r * 256 + tx * 4]) =
            *reinterpret_cast<const vf4*>(slice + (long)(g0 + r) * 256 + tx * 4);
    }
    __syncthreads();

    // ---- scatter to 9 d-shifted planes ----
    #pragma unroll
    for (int d = 0; d < 9; ++d) {
        int t = (d - 4) * a4;
        float* __restrict__ oplane = out + ((long)(d * 16 + c) * 9 + a) * 65536L;
        int tq = t >> 2;                    // arithmetic shift = floor div
        switch (t & 3) {
        case 0: emit_plane<0>(lds_t, oplane, g0, t, tq, tx, ty); break;
        case 1: emit_plane<1>(lds_t, oplane, g0, t, tq, tx, ty); break;
        case 2: emit_plane<2>(lds_t, oplane, g0, t, tq, tx, ty); break;
        case 3: emit_plane<3>(lds_t, oplane, g0, t, tq, tx, ty); break;
        }

        // ---- distributed zero-fill: block bi fills zero-row bi (if any) ----
        int zn = t < 0 ? -t : t;            // 0..16 uncovered rows per plane
        int z0 = t > 0 ? 0 : 256 + t;
        if (zn && ty == (d & 3) && (int)blockIdx.x < zn) {
            float* __restrict__ orow = oplane + (long)(z0 + (int)blockIdx.x) * 256;
            vf4 z = {0.f, 0.f, 0.f, 0.f};
            __builtin_nontemporal_store(z, reinterpret_cast<vf4*>(orow + tx * 4));
        }
    }
}

extern "C" void kernel_launch(void* const* d_in, const int* in_sizes, int n_in,
                              void* d_out, int out_size, void* d_ws, size_t ws_size,
                              hipStream_t stream)
{
    const float* in = (const float*)d_in[0];
    float* out = (float*)d_out;

    dim3 block(64, 4, 1);    // 256 threads = 4 waves
    dim3 grid(16, 144, 1);   // 16 input y-tiles x (16 c * 9 a)
    cost_volume_kernel<<<grid, block, 0, stream>>>(in, out);
}